// Round 1
// baseline (57.456 us; speedup 1.0000x reference)
//
#include <hip/hip_runtime.h>

typedef __attribute__((ext_vector_type(8))) short short8;
typedef __attribute__((ext_vector_type(4))) float f32x4;
typedef __attribute__((ext_vector_type(4))) unsigned short us4;

#define WPB 8                        // waves per block
#define BLOCK (WPB * 64)
#define W_PITCH 528                  // bytes per W^T row: 256 bf16 + 16B pad
#define W_MAT (64 * W_PITCH)         // 33792
#define QK_PITCH 144                 // bytes per Q/K row: 64 bf16 + 16B pad
#define QK_TILE (16 * QK_PITCH)      // 2304
#define LDS_W (2 * W_MAT)            // 67584
#define LDS_TOTAL (LDS_W + WPB * 2 * QK_TILE)  // 104448

__device__ __forceinline__ unsigned short f2bf(float f) {
  unsigned u = __float_as_uint(f);
  u += 0x7FFFu + ((u >> 16) & 1u);   // round-to-nearest-even
  return (unsigned short)(u >> 16);
}

__global__ __launch_bounds__(BLOCK) void attrouter_kernel(
    const float* __restrict__ ig, const float* __restrict__ qev,
    const float* __restrict__ kev, const float* __restrict__ Wq,
    const float* __restrict__ Wk, float* __restrict__ out, int ntok)
{
  extern __shared__ char smem[];
  const int tid  = threadIdx.x;
  const int lane = tid & 63;
  const int wv   = tid >> 6;
  const int e    = lane & 15;   // A-frag row / C-frag col
  const int g    = lane >> 4;   // quarter-wave group

  // ---- stage W^T (bf16) into LDS: transpose 4x4 tiles in registers ----
  {
    const float* Wm[2] = {Wq, Wk};
    #pragma unroll
    for (int i = 0; i < 4; ++i) {
      int tile = tid + i * BLOCK;          // 0..2047
      int m  = tile >> 10;                 // matrix 0/1
      int r  = tile & 1023;
      int d0 = (r >> 4) * 4;               // 0..252
      int a0 = (r & 15) * 4;               // 0..60
      const float* src = Wm[m] + d0 * 64 + a0;
      float4 r0 = *(const float4*)(src);
      float4 r1 = *(const float4*)(src + 64);
      float4 r2 = *(const float4*)(src + 128);
      float4 r3 = *(const float4*)(src + 192);
      float c0[4] = {r0.x, r0.y, r0.z, r0.w};
      float c1[4] = {r1.x, r1.y, r1.z, r1.w};
      float c2[4] = {r2.x, r2.y, r2.z, r2.w};
      float c3[4] = {r3.x, r3.y, r3.z, r3.w};
      #pragma unroll
      for (int j = 0; j < 4; ++j) {
        us4 v;
        v[0] = f2bf(c0[j]); v[1] = f2bf(c1[j]);
        v[2] = f2bf(c2[j]); v[3] = f2bf(c3[j]);
        *(us4*)(smem + m * W_MAT + (a0 + j) * W_PITCH + d0 * 2) = v;
      }
    }
  }
  __syncthreads();

  char* qB = smem + LDS_W + wv * (2 * QK_TILE);
  char* kB = qB + QK_TILE;
  unsigned short* qw = (unsigned short*)qB;
  unsigned short* kw = (unsigned short*)kB;

  const int nwaves = gridDim.x * WPB;
  for (int tok = blockIdx.x * WPB + wv; tok < ntok; tok += nwaves) {
    const float* qrow = qev + (size_t)tok * 4096 + e * 256 + g * 8;
    const float* krow = kev + (size_t)tok * 4096 + e * 256 + g * 8;

    f32x4 accq[4] = {{0,0,0,0},{0,0,0,0},{0,0,0,0},{0,0,0,0}};
    f32x4 acck[4] = {{0,0,0,0},{0,0,0,0},{0,0,0,0},{0,0,0,0}};

    // ---- projections: query = Xq @ Wq, key = Xk @ Wk  (bf16 MFMA) ----
    #pragma unroll
    for (int ks = 0; ks < 8; ++ks) {
      float4 x0 = *(const float4*)(qrow + ks * 32);
      float4 x1 = *(const float4*)(qrow + ks * 32 + 4);
      float4 y0 = *(const float4*)(krow + ks * 32);
      float4 y1 = *(const float4*)(krow + ks * 32 + 4);
      short8 aq, ak;
      aq[0]=f2bf(x0.x); aq[1]=f2bf(x0.y); aq[2]=f2bf(x0.z); aq[3]=f2bf(x0.w);
      aq[4]=f2bf(x1.x); aq[5]=f2bf(x1.y); aq[6]=f2bf(x1.z); aq[7]=f2bf(x1.w);
      ak[0]=f2bf(y0.x); ak[1]=f2bf(y0.y); ak[2]=f2bf(y0.z); ak[3]=f2bf(y0.w);
      ak[4]=f2bf(y1.x); ak[5]=f2bf(y1.y); ak[6]=f2bf(y1.z); ak[7]=f2bf(y1.w);
      #pragma unroll
      for (int n = 0; n < 4; ++n) {
        const int off = (n * 16 + e) * W_PITCH + ks * 64 + g * 16;
        short8 bq = *(const short8*)(smem + off);
        short8 bk = *(const short8*)(smem + W_MAT + off);
        accq[n] = __builtin_amdgcn_mfma_f32_16x16x32_bf16(aq, bq, accq[n], 0, 0, 0);
        acck[n] = __builtin_amdgcn_mfma_f32_16x16x32_bf16(ak, bk, acck[n], 0, 0, 0);
      }
    }

    // ---- C-frags -> per-wave LDS scratch (bf16) ----
    // C layout: row = g*4 + r, col = n*16 + e
    #pragma unroll
    for (int n = 0; n < 4; ++n) {
      #pragma unroll
      for (int r = 0; r < 4; ++r) {
        int idx = (g * 4 + r) * 72 + n * 16 + e;   // 72 ushorts = 144B pitch
        qw[idx] = f2bf(accq[n][r]);
        kw[idx] = f2bf(acck[n][r]);
      }
    }

    // ---- sim = Q @ K^T / 8 : both operands loaded in A-layout ----
    f32x4 s = {0, 0, 0, 0};
    #pragma unroll
    for (int ks = 0; ks < 2; ++ks) {
      short8 fq = *(const short8*)(qB + e * QK_PITCH + ks * 64 + g * 16);
      short8 fk = *(const short8*)(kB + e * QK_PITCH + ks * 64 + g * 16);
      s = __builtin_amdgcn_mfma_f32_16x16x32_bf16(fq, fk, s, 0, 0, 0);
    }

    // ---- softmax over k (lanes 0..15 of each group), gate, final softmax ----
    float gv = ig[tok * 16 + e];      // e == k-expert column here
    float ge[4];
    #pragma unroll
    for (int r = 0; r < 4; ++r) {
      float sv = s[r] * 0.125f;       // / sqrt(64)
      float mx = sv;
      mx = fmaxf(mx, __shfl_xor(mx, 1));
      mx = fmaxf(mx, __shfl_xor(mx, 2));
      mx = fmaxf(mx, __shfl_xor(mx, 4));
      mx = fmaxf(mx, __shfl_xor(mx, 8));
      float ev = __expf(sv - mx);
      float se = ev, sg = ev * gv;
      se += __shfl_xor(se, 1); sg += __shfl_xor(sg, 1);
      se += __shfl_xor(se, 2); sg += __shfl_xor(sg, 2);
      se += __shfl_xor(se, 4); sg += __shfl_xor(sg, 4);
      se += __shfl_xor(se, 8); sg += __shfl_xor(sg, 8);
      ge[r] = sg / se;                // gate for q-row g*4+r
    }

    float gm = fmaxf(fmaxf(ge[0], ge[1]), fmaxf(ge[2], ge[3]));
    gm = fmaxf(gm, __shfl_xor(gm, 16));
    gm = fmaxf(gm, __shfl_xor(gm, 32));
    float e0 = __expf(ge[0] - gm), e1 = __expf(ge[1] - gm);
    float e2 = __expf(ge[2] - gm), e3 = __expf(ge[3] - gm);
    float ss = e0 + e1 + e2 + e3;
    ss += __shfl_xor(ss, 16);
    ss += __shfl_xor(ss, 32);
    if (e == 0) {
      float inv = 1.0f / ss;
      float4 o = make_float4(e0 * inv, e1 * inv, e2 * inv, e3 * inv);
      *(float4*)(out + tok * 16 + g * 4) = o;
    }
  }
}

extern "C" void kernel_launch(void* const* d_in, const int* in_sizes, int n_in,
                              void* d_out, int out_size, void* d_ws, size_t ws_size,
                              hipStream_t stream) {
  const float* ig  = (const float*)d_in[0];
  const float* qev = (const float*)d_in[1];
  const float* kev = (const float*)d_in[2];
  const float* Wq  = (const float*)d_in[3];
  const float* Wk  = (const float*)d_in[4];
  float* out = (float*)d_out;
  int ntok = in_sizes[1] >> 12;    // B*S ( = in_sizes[1] / (16*256) )

  hipFuncSetAttribute((const void*)attrouter_kernel,
                      hipFuncAttributeMaxDynamicSharedMemorySize, LDS_TOTAL);

  int grid = 512;                  // 4096 waves -> 2 tokens/wave at ntok=8192
  attrouter_kernel<<<grid, BLOCK, LDS_TOTAL, stream>>>(ig, qev, kev, Wq, Wk, out, ntok);
}

// Round 2
// 52.827 us; speedup vs baseline: 1.0876x; 1.0876x over previous
//
#include <hip/hip_runtime.h>
#include <hip/hip_bf16.h>

typedef __attribute__((ext_vector_type(8))) short short8;
typedef __attribute__((ext_vector_type(4))) float f32x4;

#define WPB 8
#define BLOCK 512
#define W_PITCH 528                   // 256 bf16 + 16B pad (bank-spread for B-frag reads)
#define W_MAT (64 * W_PITCH)          // 33792
#define QK_PITCH 144                  // 64 bf16 + 16B pad
#define QK_TILE (16 * QK_PITCH)       // 2304
#define LDS_W (2 * W_MAT)             // 67584
#define SCR_PW (4 * QK_TILE)          // per wave: 2 double-buffered (Q,K) pairs = 9216
#define LDS_TOTAL (LDS_W + WPB * SCR_PW)  // 141312 <= 160K -> 1 block/CU, 8 waves

union S8U { short8 s; unsigned u[4]; };

__device__ __forceinline__ unsigned pk2(float a, float b) {
  __hip_bfloat162 h = __float22bfloat162_rn(make_float2(a, b));
  return *reinterpret_cast<unsigned*>(&h);
}
__device__ __forceinline__ unsigned short bf1(float a) {
  __hip_bfloat16 h = __float2bfloat16(a);
  return *reinterpret_cast<unsigned short*>(&h);
}

// load both halves (32B) of this lane's X row chunk for K-step KS, 4 tokens
#define LOADX(BUF, KS) {                                                      \
  _Pragma("unroll") for (int t = 0; t < 4; ++t) {                             \
    BUF[t][0] = *(const float4*)(xr[t] + (KS) * 32);                          \
    BUF[t][1] = *(const float4*)(xr[t] + (KS) * 32 + 4);                      \
  } }

// convert + 4 B-frag reads + 16 MFMAs for K-step KS
#define STEP(BUF, KS, WLDS, ACC) {                                            \
  short8 af[4];                                                               \
  _Pragma("unroll") for (int t = 0; t < 4; ++t) {                             \
    S8U u_;                                                                   \
    u_.u[0] = pk2(BUF[t][0].x, BUF[t][0].y);                                  \
    u_.u[1] = pk2(BUF[t][0].z, BUF[t][0].w);                                  \
    u_.u[2] = pk2(BUF[t][1].x, BUF[t][1].y);                                  \
    u_.u[3] = pk2(BUF[t][1].z, BUF[t][1].w);                                  \
    af[t] = u_.s;                                                             \
  }                                                                           \
  _Pragma("unroll") for (int n = 0; n < 4; ++n) {                             \
    short8 bfr = *(const short8*)((WLDS) + (n * 16 + e) * W_PITCH + (KS) * 64 + g * 16); \
    _Pragma("unroll") for (int t = 0; t < 4; ++t)                             \
      ACC[t][n] = __builtin_amdgcn_mfma_f32_16x16x32_bf16(af[t], bfr, ACC[t][n], 0, 0, 0); \
  } }

// full 8-step projection pass for one matrix, 2-stage pipelined
#define PROJ_PASS(XBASE, WLDS, ACC) {                                         \
  const float* xr[4];                                                         \
  _Pragma("unroll") for (int t = 0; t < 4; ++t)                               \
    xr[t] = (XBASE) + (size_t)tk[t] * 4096 + e * 256 + g * 8;                 \
  float4 b0[4][2], b1[4][2];                                                  \
  LOADX(b0, 0); LOADX(b1, 1);                                                 \
  _Pragma("unroll") for (int kp = 0; kp < 4; ++kp) {                          \
    STEP(b0, 2 * kp, WLDS, ACC);                                              \
    if (kp < 3) LOADX(b0, 2 * kp + 2);                                        \
    STEP(b1, 2 * kp + 1, WLDS, ACC);                                          \
    if (kp < 3) LOADX(b1, 2 * kp + 3);                                        \
  } }

// C-frag (row=g*4+r, col=n*16+e) -> row-major bf16 scratch
#define WRITEQK(T, QB, KB) {                                                  \
  unsigned short* qw_ = (unsigned short*)(QB);                                \
  unsigned short* kw_ = (unsigned short*)(KB);                                \
  _Pragma("unroll") for (int n = 0; n < 4; ++n)                               \
    _Pragma("unroll") for (int r = 0; r < 4; ++r) {                           \
      int idx_ = (g * 4 + r) * 72 + n * 16 + e;                               \
      qw_[idx_] = bf1(aq[T][n][r]);                                           \
      kw_[idx_] = bf1(ak[T][n][r]);                                           \
    } }

// sim^T = mfma(K, Q): lane(e,g) reg r = sim[q=e][k=g*4+r]; softmax over k is
// 3 in-lane adds + xor16/xor32; final 16-way softmax = xor1/2/4/8.
#define ATT(T, QB, KB) {                                                      \
  f32x4 s_ = {0, 0, 0, 0};                                                    \
  _Pragma("unroll") for (int ks2 = 0; ks2 < 2; ++ks2) {                       \
    short8 fk_ = *(const short8*)((KB) + e * QK_PITCH + ks2 * 64 + g * 16);   \
    short8 fq_ = *(const short8*)((QB) + e * QK_PITCH + ks2 * 64 + g * 16);   \
    s_ = __builtin_amdgcn_mfma_f32_16x16x32_bf16(fk_, fq_, s_, 0, 0, 0);      \
  }                                                                           \
  float4 igv_ = *(const float4*)(ig + (size_t)tk[T] * 16 + g * 4);            \
  float p0_ = __expf(s_[0]), p1_ = __expf(s_[1]);                             \
  float p2_ = __expf(s_[2]), p3_ = __expf(s_[3]);                             \
  float sg_ = p0_ * igv_.x + p1_ * igv_.y + p2_ * igv_.z + p3_ * igv_.w;      \
  float se_ = (p0_ + p1_) + (p2_ + p3_);                                      \
  sg_ += __shfl_xor(sg_, 16); se_ += __shfl_xor(se_, 16);                     \
  sg_ += __shfl_xor(sg_, 32); se_ += __shfl_xor(se_, 32);                     \
  float ev_ = __expf(sg_ / se_);                                              \
  float ss_ = ev_;                                                            \
  ss_ += __shfl_xor(ss_, 1); ss_ += __shfl_xor(ss_, 2);                       \
  ss_ += __shfl_xor(ss_, 4); ss_ += __shfl_xor(ss_, 8);                       \
  if (g == 0 && wbase + (T) < ntok) out[(size_t)tk[T] * 16 + e] = ev_ / ss_;  \
}

__global__ __launch_bounds__(BLOCK, 2) void attrouter_kernel(
    const float* __restrict__ ig, const float* __restrict__ qev,
    const float* __restrict__ kev, const float* __restrict__ Wq,
    const float* __restrict__ Wk, float* __restrict__ out, int ntok)
{
  extern __shared__ char smem[];
  const int tid  = threadIdx.x;
  const int lane = tid & 63;
  const int wv   = tid >> 6;
  const int e    = lane & 15;
  const int g    = lane >> 4;

  // ---- stage W^T (bf16) into LDS; fold 1/sqrt(64) into Wq (exact 2^-3) ----
  {
    #pragma unroll
    for (int i = 0; i < 4; ++i) {
      int tile = tid + i * BLOCK;            // 0..2047
      int m  = tile >> 10;
      int r  = tile & 1023;
      int d0 = (r >> 4) * 4;
      int a0 = (r & 15) * 4;
      const float* wsrc = m ? Wk : Wq;
      const float scl = m ? 1.0f : 0.125f;
      const float* src = wsrc + d0 * 64 + a0;
      float4 r0 = *(const float4*)(src);
      float4 r1 = *(const float4*)(src + 64);
      float4 r2 = *(const float4*)(src + 128);
      float4 r3 = *(const float4*)(src + 192);
      float c0[4] = {r0.x, r0.y, r0.z, r0.w};
      float c1[4] = {r1.x, r1.y, r1.z, r1.w};
      float c2[4] = {r2.x, r2.y, r2.z, r2.w};
      float c3[4] = {r3.x, r3.y, r3.z, r3.w};
      #pragma unroll
      for (int j = 0; j < 4; ++j) {
        uint2 v;
        v.x = pk2(scl * c0[j], scl * c1[j]);
        v.y = pk2(scl * c2[j], scl * c3[j]);
        *(uint2*)(smem + m * W_MAT + (a0 + j) * W_PITCH + d0 * 2) = v;
      }
    }
  }
  __syncthreads();

  const int wbase = (blockIdx.x * WPB + wv) * 4;
  if (wbase >= ntok) return;      // no barriers after this point

  char* scr = smem + LDS_W + wv * SCR_PW;
  char* qb0 = scr;
  char* kb0 = scr + QK_TILE;
  char* qb1 = scr + 2 * QK_TILE;
  char* kb1 = scr + 3 * QK_TILE;

  int tk[4];
  #pragma unroll
  for (int t = 0; t < 4; ++t)
    tk[t] = (wbase + t < ntok) ? (wbase + t) : (ntok - 1);

  f32x4 aq[4][4] = {}; f32x4 ak[4][4] = {};

  PROJ_PASS(qev, smem, aq);
  PROJ_PASS(kev, smem + W_MAT, ak);

  WRITEQK(0, qb0, kb0);
  WRITEQK(1, qb1, kb1);
  ATT(0, qb0, kb0);
  ATT(1, qb1, kb1);
  WRITEQK(2, qb0, kb0);
  WRITEQK(3, qb1, kb1);
  ATT(2, qb0, kb0);
  ATT(3, qb1, kb1);
}

extern "C" void kernel_launch(void* const* d_in, const int* in_sizes, int n_in,
                              void* d_out, int out_size, void* d_ws, size_t ws_size,
                              hipStream_t stream) {
  const float* ig  = (const float*)d_in[0];
  const float* qev = (const float*)d_in[1];
  const float* kev = (const float*)d_in[2];
  const float* Wq  = (const float*)d_in[3];
  const float* Wk  = (const float*)d_in[4];
  float* out = (float*)d_out;
  int ntok = in_sizes[1] >> 12;    // B*S

  hipFuncSetAttribute((const void*)attrouter_kernel,
                      hipFuncAttributeMaxDynamicSharedMemorySize, LDS_TOTAL);

  int grid = (ntok + WPB * 4 - 1) / (WPB * 4);   // 256 at ntok=8192 -> 1 block/CU
  attrouter_kernel<<<grid, BLOCK, LDS_TOTAL, stream>>>(ig, qev, kev, Wq, Wk, out, ntok);
}

// Round 3
// 49.580 us; speedup vs baseline: 1.1588x; 1.0655x over previous
//
#include <hip/hip_runtime.h>
#include <hip/hip_bf16.h>

typedef __attribute__((ext_vector_type(8))) short short8;
typedef __attribute__((ext_vector_type(4))) float f32x4;

#define WPB 16
#define BLOCK 1024
#define TPW 2                         // sequential tokens per wave
#define W_PITCH 528                   // 256 bf16 + 16B pad
#define W_MAT (64 * W_PITCH)          // 33792
#define QK_PITCH 144                  // 64 bf16 + 16B pad
#define QK_TILE (16 * QK_PITCH)       // 2304
#define LDS_W (2 * W_MAT)             // 67584
#define SCR_PW (2 * QK_TILE)          // Q tile + K tile per wave = 4608
#define LDS_TOTAL (LDS_W + WPB * SCR_PW)  // 141312 -> one 16-wave block/CU = 4 waves/SIMD

union S8U { short8 s; unsigned u[4]; };

__device__ __forceinline__ unsigned pk2(float a, float b) {
  __hip_bfloat162 h = __float22bfloat162_rn(make_float2(a, b));
  return *reinterpret_cast<unsigned*>(&h);
}
__device__ __forceinline__ unsigned short bf1(float a) {
  __hip_bfloat16 h = __float2bfloat16(a);
  return *reinterpret_cast<unsigned short*>(&h);
}

#define LOAD2(B, XROW, KS) {                                                  \
  B[0] = *(const float4*)((XROW) + (KS) * 32);                                \
  B[1] = *(const float4*)((XROW) + (KS) * 32 + 4); }

// convert one token's 32B chunk + 4 B-frag reads + 4 MFMAs
#define STEP1(B, KS, WLDS, ACC) {                                             \
  S8U u_;                                                                     \
  u_.u[0] = pk2(B[0].x, B[0].y);  u_.u[1] = pk2(B[0].z, B[0].w);              \
  u_.u[2] = pk2(B[1].x, B[1].y);  u_.u[3] = pk2(B[1].z, B[1].w);              \
  short8 af_ = u_.s;                                                          \
  _Pragma("unroll") for (int n = 0; n < 4; ++n) {                             \
    short8 bf_ = *(const short8*)((WLDS) + (n * 16 + e) * W_PITCH + (KS) * 64 + g * 16); \
    ACC[n] = __builtin_amdgcn_mfma_f32_16x16x32_bf16(af_, bf_, ACC[n], 0, 0, 0); \
  } }

// 8 K-steps, 2-stage software pipeline
#define PROJ1(XROW, WLDS, ACC) {                                              \
  float4 b0_[2], b1_[2];                                                      \
  LOAD2(b0_, XROW, 0); LOAD2(b1_, XROW, 1);                                   \
  _Pragma("unroll") for (int kp = 0; kp < 4; ++kp) {                          \
    STEP1(b0_, 2 * kp, WLDS, ACC);                                            \
    if (kp < 3) LOAD2(b0_, XROW, 2 * kp + 2);                                 \
    STEP1(b1_, 2 * kp + 1, WLDS, ACC);                                        \
    if (kp < 3) LOAD2(b1_, XROW, 2 * kp + 3);                                 \
  } }

// C-frag (row=g*4+r, col=n*16+e) -> row-major bf16 tile
#define WRITET(ACC, TB) {                                                     \
  unsigned short* tw_ = (unsigned short*)(TB);                                \
  _Pragma("unroll") for (int n = 0; n < 4; ++n)                               \
    _Pragma("unroll") for (int r = 0; r < 4; ++r)                             \
      tw_[(g * 4 + r) * 72 + n * 16 + e] = bf1(ACC[n][r]); }

__global__ __launch_bounds__(BLOCK) void attrouter_kernel(
    const float* __restrict__ ig, const float* __restrict__ qev,
    const float* __restrict__ kev, const float* __restrict__ Wq,
    const float* __restrict__ Wk, float* __restrict__ out, int ntok)
{
  extern __shared__ char smem[];
  const int tid  = threadIdx.x;
  const int lane = tid & 63;
  const int wv   = tid >> 6;
  const int e    = lane & 15;
  const int g    = lane >> 4;

  // ---- stage W^T (bf16) into LDS; fold 1/sqrt(64) into Wq (exact 2^-3) ----
  {
    #pragma unroll
    for (int i = 0; i < 2; ++i) {
      int tile = tid + i * BLOCK;            // 0..2047
      int m  = tile >> 10;
      int r  = tile & 1023;
      int d0 = (r >> 4) * 4;
      int a0 = (r & 15) * 4;
      const float* wsrc = m ? Wk : Wq;
      const float scl = m ? 1.0f : 0.125f;
      const float* src = wsrc + d0 * 64 + a0;
      float4 r0 = *(const float4*)(src);
      float4 r1 = *(const float4*)(src + 64);
      float4 r2 = *(const float4*)(src + 128);
      float4 r3 = *(const float4*)(src + 192);
      float c0[4] = {r0.x, r0.y, r0.z, r0.w};
      float c1[4] = {r1.x, r1.y, r1.z, r1.w};
      float c2[4] = {r2.x, r2.y, r2.z, r2.w};
      float c3[4] = {r3.x, r3.y, r3.z, r3.w};
      #pragma unroll
      for (int j = 0; j < 4; ++j) {
        uint2 v;
        v.x = pk2(scl * c0[j], scl * c1[j]);
        v.y = pk2(scl * c2[j], scl * c3[j]);
        *(uint2*)(smem + m * W_MAT + (a0 + j) * W_PITCH + d0 * 2) = v;
      }
    }
  }
  __syncthreads();

  char* qt = smem + LDS_W + wv * SCR_PW;
  char* kt = qt + QK_TILE;

  const int wbase = (blockIdx.x * WPB + wv) * TPW;

  #pragma unroll
  for (int t = 0; t < TPW; ++t) {
    const int tok = wbase + t;
    if (tok >= ntok) break;
    const float* qrow = qev + (size_t)tok * 4096 + e * 256 + g * 8;
    const float* krow = kev + (size_t)tok * 4096 + e * 256 + g * 8;

    // ---- Q projection ----
    f32x4 aq[4] = {{0,0,0,0},{0,0,0,0},{0,0,0,0},{0,0,0,0}};
    PROJ1(qrow, smem, aq);
    WRITET(aq, qt);

    // ---- K projection (Q-acc regs now free) ----
    f32x4 ak[4] = {{0,0,0,0},{0,0,0,0},{0,0,0,0},{0,0,0,0}};
    PROJ1(krow, smem + W_MAT, ak);
    WRITET(ak, kt);

    // ---- sim^T = mfma(K, Q): lane(e,g) reg r = sim[q=e][k=g*4+r] ----
    short8 fq0 = *(const short8*)(qt + e * QK_PITCH + g * 16);
    short8 fq1 = *(const short8*)(qt + e * QK_PITCH + 64 + g * 16);
    short8 fk0 = *(const short8*)(kt + e * QK_PITCH + g * 16);
    short8 fk1 = *(const short8*)(kt + e * QK_PITCH + 64 + g * 16);
    f32x4 s = {0, 0, 0, 0};
    s = __builtin_amdgcn_mfma_f32_16x16x32_bf16(fk0, fq0, s, 0, 0, 0);
    s = __builtin_amdgcn_mfma_f32_16x16x32_bf16(fk1, fq1, s, 0, 0, 0);

    // ---- softmax over k (in-lane + xor16/32), gate, final 16-way softmax ----
    float4 igv = *(const float4*)(ig + (size_t)tok * 16 + g * 4);
    float p0 = __expf(s[0]), p1 = __expf(s[1]);
    float p2 = __expf(s[2]), p3 = __expf(s[3]);
    float sg = p0 * igv.x + p1 * igv.y + p2 * igv.z + p3 * igv.w;
    float se = (p0 + p1) + (p2 + p3);
    sg += __shfl_xor(sg, 16); se += __shfl_xor(se, 16);
    sg += __shfl_xor(sg, 32); se += __shfl_xor(se, 32);
    float ev = __expf(sg / se);
    float ss = ev;
    ss += __shfl_xor(ss, 1); ss += __shfl_xor(ss, 2);
    ss += __shfl_xor(ss, 4); ss += __shfl_xor(ss, 8);
    if (g == 0) out[(size_t)tok * 16 + e] = ev / ss;
  }
}

extern "C" void kernel_launch(void* const* d_in, const int* in_sizes, int n_in,
                              void* d_out, int out_size, void* d_ws, size_t ws_size,
                              hipStream_t stream) {
  const float* ig  = (const float*)d_in[0];
  const float* qev = (const float*)d_in[1];
  const float* kev = (const float*)d_in[2];
  const float* Wq  = (const float*)d_in[3];
  const float* Wk  = (const float*)d_in[4];
  float* out = (float*)d_out;
  int ntok = in_sizes[1] >> 12;    // B*S

  hipFuncSetAttribute((const void*)attrouter_kernel,
                      hipFuncAttributeMaxDynamicSharedMemorySize, LDS_TOTAL);

  int grid = (ntok + WPB * TPW - 1) / (WPB * TPW);   // 256 at ntok=8192
  attrouter_kernel<<<grid, BLOCK, LDS_TOTAL, stream>>>(ig, qev, kev, Wq, Wk, out, ntok);
}